// Round 2
// baseline (1038.325 us; speedup 1.0000x reference)
//
#include <hip/hip_runtime.h>
#include <math.h>

#define CLS_THRESH 0.05f
#define NEG_INF (-__builtin_inff())

__device__ __forceinline__ void upd4(float& b, int& bi, const float4 v, const int base) {
    if (v.x > b) { b = v.x; bi = base;     }
    if (v.y > b) { b = v.y; bi = base + 1; }
    if (v.z > b) { b = v.z; bi = base + 2; }
    if (v.w > b) { b = v.w; bi = base + 3; }
}

__device__ __forceinline__ void epilogue(
    float best, int bidx, int row, int N, int rows,
    const float* __restrict__ reg, const float* __restrict__ anch,
    float* __restrict__ out, float img_w, float img_h)
{
    const int n = row % N;
    const float4 rg = reinterpret_cast<const float4*>(reg)[row];
    const float4 an = reinterpret_cast<const float4*>(anch)[n];

    const float w  = an.z - an.x;
    const float h  = an.w - an.y;
    const float cx = an.x + 0.5f * w;
    const float cy = an.y + 0.5f * h;

    const float pcx = cx + rg.x * 0.1f * w;
    const float pcy = cy + rg.y * 0.1f * h;
    const float pw  = expf(rg.z * 0.2f) * w;
    const float ph  = expf(rg.w * 0.2f) * h;

    float x1 = fminf(fmaxf(pcx - 0.5f * pw, 0.0f), img_w);
    float y1 = fminf(fmaxf(pcy - 0.5f * ph, 0.0f), img_h);
    float x2 = fminf(fmaxf(pcx + 0.5f * pw, 0.0f), img_w);
    float y2 = fminf(fmaxf(pcy + 0.5f * ph, 0.0f), img_h);

    const float m = (best > CLS_THRESH) ? 1.0f : 0.0f;

    reinterpret_cast<float4*>(out)[row] = make_float4(x1 * m, y1 * m, x2 * m, y2 * m);
    out[(long long)rows * 4 + row] = best * m;     // scores_m
    out[(long long)rows * 5 + row] = (float)bidx;  // cls_idx
    out[(long long)rows * 6 + row] = m;            // mask
}

// Grid-stride persistent kernel: one wave per row, two rows in flight per
// iteration (4 coalesced float4 loads issued before any reduce VALU).
__global__ __launch_bounds__(256) void infer_transform_kernel(
    const float* __restrict__ cls,   // [rows, C]
    const float* __restrict__ reg,   // [rows, 4]
    const float* __restrict__ anch,  // [N, 4]
    float* __restrict__ out,
    int N, int C, int rows, float img_w, float img_h)
{
    const int lane = threadIdx.x & 63;
    const int wid  = blockIdx.x * (blockDim.x >> 6) + (threadIdx.x >> 6);
    const int nW   = gridDim.x * (blockDim.x >> 6);
    const int nvec = C >> 2;

    if (nvec <= 128 && (C & 3) == 0) {
        // Specialized: a row is covered by float4 chunks i=lane and i=lane+64.
        for (int r0 = wid; r0 < rows; r0 += 2 * nW) {
            const int  r1   = r0 + nW;
            const bool has1 = r1 < rows;
            const float4* c0 = reinterpret_cast<const float4*>(cls + (long long)r0 * C);
            const float4* c1 = reinterpret_cast<const float4*>(cls + (long long)(has1 ? r1 : r0) * C);

            // Issue all loads first (MLP), then reduce.
            const float4 a0 = c0[lane];
            const float4 a1 = c1[lane];
            const bool hi = (lane + 64) < nvec;
            float4 d0, d1;
            if (hi) { d0 = c0[lane + 64]; d1 = c1[lane + 64]; }

            float b0 = NEG_INF, b1 = NEG_INF;
            int   j0 = 0,       j1 = 0;
            upd4(b0, j0, a0, lane << 2);
            upd4(b1, j1, a1, lane << 2);
            if (hi) {
                upd4(b0, j0, d0, (lane + 64) << 2);
                upd4(b1, j1, d1, (lane + 64) << 2);
            }

            // Interleaved dual butterfly reduce (max, first-index tie-break).
            #pragma unroll
            for (int off = 32; off >= 1; off >>= 1) {
                const float o0v = __shfl_xor(b0, off, 64);
                const int   o0j = __shfl_xor(j0, off, 64);
                const float o1v = __shfl_xor(b1, off, 64);
                const int   o1j = __shfl_xor(j1, off, 64);
                if (o0v > b0 || (o0v == b0 && o0j < j0)) { b0 = o0v; j0 = o0j; }
                if (o1v > b1 || (o1v == b1 && o1j < j1)) { b1 = o1v; j1 = o1j; }
            }

            if (lane == 0) {
                epilogue(b0, j0, r0, N, rows, reg, anch, out, img_w, img_h);
                if (has1) epilogue(b1, j1, r1, N, rows, reg, anch, out, img_w, img_h);
            }
        }
    } else {
        // Generic fallback for other shapes.
        for (int row = wid; row < rows; row += nW) {
            const float* crow = cls + (long long)row * C;
            float b = NEG_INF; int j = 0;
            for (int i = lane; i < nvec; i += 64)
                upd4(b, j, reinterpret_cast<const float4*>(crow)[i], i << 2);
            for (int i = (nvec << 2) + lane; i < C; i += 64) {
                const float v = crow[i];
                if (v > b) { b = v; j = i; }
            }
            #pragma unroll
            for (int off = 32; off >= 1; off >>= 1) {
                const float ov = __shfl_xor(b, off, 64);
                const int   oj = __shfl_xor(j, off, 64);
                if (ov > b || (ov == b && oj < j)) { b = ov; j = oj; }
            }
            if (lane == 0) epilogue(b, j, row, N, rows, reg, anch, out, img_w, img_h);
        }
    }
}

extern "C" void kernel_launch(void* const* d_in, const int* in_sizes, int n_in,
                              void* d_out, int out_size, void* d_ws, size_t ws_size,
                              hipStream_t stream) {
    // setup_inputs() order: imgs, classifications, regressions, anchors
    const float* cls  = (const float*)d_in[1];
    const float* reg  = (const float*)d_in[2];
    const float* anch = (const float*)d_in[3];
    float* out = (float*)d_out;

    const int N    = in_sizes[3] / 4;                    // anchors: [1, N, 4]
    const int rows = in_sizes[2] / 4;                    // regressions: [B, N, 4] -> B*N
    const int B    = rows / N;
    const int C    = (int)((long long)in_sizes[1] / rows);
    const long long hw = (long long)in_sizes[0] / (3LL * B);
    const int W = (int)(sqrt((double)hw) + 0.5);         // imgs: [B, 3, H, W], H == W
    const float img_w = (float)W, img_h = (float)W;

    // Persistent grid: 256 CU x 8 blocks/CU of 256 threads (4 waves).
    int blocks = 2048;
    const int max_needed = (rows + 3) / 4;               // >=1 row per wave
    if (blocks > max_needed) blocks = max_needed;

    infer_transform_kernel<<<blocks, 256, 0, stream>>>(cls, reg, anch, out,
                                                       N, C, rows, img_w, img_h);
}